// Round 1
// baseline (1238.197 us; speedup 1.0000x reference)
//
#include <hip/hip_runtime.h>
#include <math.h>

#define NN 10000
#define NE 160000
#define NG 64
#define FEAT 80
#define NT 5
#define NL 4

// ---------------- setup kernels ----------------
__global__ void k_count(const int* __restrict__ dst, int* __restrict__ deg) {
    int e = blockIdx.x * 256 + threadIdx.x;
    if (e < NE) atomicAdd(&deg[dst[e]], 1);
}

__global__ void k_gcnt(const int* __restrict__ batch, int* __restrict__ gcnt) {
    int n = blockIdx.x * 256 + threadIdx.x;
    if (n < NN) atomicAdd(&gcnt[batch[n]], 1);
}

__global__ void k_scan(const int* __restrict__ deg, int* __restrict__ offs) {
    __shared__ int sums[256];
    int tid = threadIdx.x;
    int start = tid * 40, stop = min(start + 40, NN);
    int s = 0;
    for (int i = start; i < stop; ++i) s += deg[i];
    sums[tid] = s;
    __syncthreads();
    for (int off = 1; off < 256; off <<= 1) {
        int v = (tid >= off) ? sums[tid - off] : 0;
        __syncthreads();
        sums[tid] += v;
        __syncthreads();
    }
    int base = (tid == 0) ? 0 : sums[tid - 1];
    for (int i = start; i < stop; ++i) { offs[i] = base; base += deg[i]; }
    if (tid == 255) offs[NN] = sums[255];
}

__global__ void k_ald(const int* __restrict__ deg, float* __restrict__ ald) {
    __shared__ float red[256];
    int i = blockIdx.x * 256 + threadIdx.x;
    red[threadIdx.x] = (i < NN) ? logf((float)deg[i] + 1.0f) : 0.0f;
    __syncthreads();
    for (int s = 128; s > 0; s >>= 1) {
        if (threadIdx.x < s) red[threadIdx.x] += red[threadIdx.x + s];
        __syncthreads();
    }
    if (threadIdx.x == 0) atomicAdd(ald, red[0]);
}

__global__ void k_fill(const int* __restrict__ src, const int* __restrict__ dst,
                       const int* __restrict__ offs, int* __restrict__ cursor,
                       int* __restrict__ csr) {
    int e = blockIdx.x * 256 + threadIdx.x;
    if (e < NE) {
        int d = dst[e];
        int p = atomicAdd(&cursor[d], 1);
        csr[offs[d] + p] = src[e];
    }
}

// hT is feature-major: hT[f*NN + n]
__global__ void k_op0(const float* __restrict__ x, const float* __restrict__ plW,
                      const float* __restrict__ plb, float* __restrict__ hT) {
    int i = blockIdx.x * 256 + threadIdx.x;  // i = f*NN + n
    if (i < FEAT * NN) {
        int f = i / NN, n = i - f * NN;
        hT[i] = x[2 * n] * plW[f] + plb[f];
    }
}

// ---------------- per-layer kernels ----------------
// A[n][c] (c = t*80+o, c<400) = sum_f h[n][f] * preW[t][f][o]        (dst half)
// B[n][c]                     = sum_f h[n][f] * preW[t][80+f][o]     (src half)
__global__ __launch_bounds__(256) void k_mm_ab(
        const float* __restrict__ hT, const float* __restrict__ preW_l,
        float* __restrict__ A, float* __restrict__ B) {
    __shared__ float hs[16][80];
    int n0 = blockIdx.x * 16;
    int tid = threadIdx.x;
    for (int i = tid; i < 16 * 80; i += 256) {
        int nl = i & 15, f = i >> 4;
        hs[nl][f] = hT[(size_t)f * NN + n0 + nl];
    }
    __syncthreads();
    int c0 = blockIdx.y * 512 + tid;  // slot0: c0, slot1: c0+256; combined c in [0,800)
    float acc[2][16];
#pragma unroll
    for (int s = 0; s < 2; s++)
#pragma unroll
        for (int i = 0; i < 16; i++) acc[s][i] = 0.f;
    const float* wp[2];
#pragma unroll
    for (int s = 0; s < 2; s++) {
        int c = c0 + s * 256;
        int part = (c >= 400) ? 1 : 0;
        int cc = c - part * 400;
        int t = cc / 80, o = cc - t * 80;
        wp[s] = preW_l + (size_t)(t * 160 + part * 80) * 80 + o;  // + f*80 per f
    }
    bool act1 = (c0 + 256) < 800;
    for (int fq = 0; fq < 80; fq += 4) {
        float w0a = wp[0][(fq + 0) * 80], w0b = wp[0][(fq + 1) * 80];
        float w0c = wp[0][(fq + 2) * 80], w0d = wp[0][(fq + 3) * 80];
        float w1a = 0.f, w1b = 0.f, w1c = 0.f, w1d = 0.f;
        if (act1) {
            w1a = wp[1][(fq + 0) * 80]; w1b = wp[1][(fq + 1) * 80];
            w1c = wp[1][(fq + 2) * 80]; w1d = wp[1][(fq + 3) * 80];
        }
#pragma unroll
        for (int i = 0; i < 16; i++) {
            float4 hv = *(const float4*)&hs[i][fq];
            acc[0][i] += hv.x * w0a + hv.y * w0b + hv.z * w0c + hv.w * w0d;
            acc[1][i] += hv.x * w1a + hv.y * w1b + hv.z * w1c + hv.w * w1d;
        }
    }
#pragma unroll
    for (int s = 0; s < 2; s++) {
        int c = c0 + s * 256;
        if (c < 800) {
            int part = (c >= 400) ? 1 : 0;
            int cc = c - part * 400;
            float* outp = part ? B : A;
#pragma unroll
            for (int i = 0; i < 16; i++) outp[(size_t)(n0 + i) * 400 + cc] = acc[s][i];
        }
    }
}

__device__ __forceinline__ void emit_agg(int n, int c, int d, float degf,
                                         float sum, float sq, float mnv, float mxv,
                                         const float* __restrict__ A,
                                         const float* __restrict__ preb_l,
                                         float* __restrict__ agg) {
    int t = c / 80, o = c - t * 80;
    float a = A[(size_t)n * 400 + c] + preb_l[t * 80 + o];
    float cnt = fmaxf(degf, 1.f);
    float mean = (degf * a + sum) / cnt;
    float msq  = (degf * a * a + 2.f * a * sum + sq) / cnt;
    float mnr = (d > 0) ? a + mnv : 0.f;
    float mxr = (d > 0) ? a + mxv : 0.f;
    float var = fmaxf(msq - mean * mean, 0.f);
    float sd = sqrtf(var + 1e-5f);
    float* bp = agg + ((size_t)n * 5 + t) * 320 + o;  // [mean|min|max|std] blocks of 80
    bp[0] = mean; bp[80] = mnr; bp[160] = mxr; bp[240] = sd;
}

__global__ __launch_bounds__(128) void k_agg(
        const float* __restrict__ A, const float* __restrict__ B,
        const int* __restrict__ offs, const int* __restrict__ csr,
        const float* __restrict__ preb_l, const float* __restrict__ ald_sum,
        float* __restrict__ agg) {
    int n = blockIdx.x;
    int tid = threadIdx.x;  // 128 threads cover c = tid, +128, +256 (+384 for tid<16)
    int e0 = offs[n], e1 = offs[n + 1];
    int d = e1 - e0;
    float s0 = 0, s1 = 0, s2 = 0, s3 = 0, q0 = 0, q1 = 0, q2 = 0, q3 = 0;
    float mn0 = 3.4e38f, mn1 = 3.4e38f, mn2 = 3.4e38f, mn3 = 3.4e38f;
    float mx0 = -3.4e38f, mx1 = -3.4e38f, mx2 = -3.4e38f, mx3 = -3.4e38f;
    bool a3 = (tid < 16);
    for (int k = e0; k < e1; ++k) {
        const float* br = B + (size_t)csr[k] * 400;
        float b0 = br[tid], b1 = br[tid + 128], b2 = br[tid + 256];
        s0 += b0; q0 += b0 * b0; mn0 = fminf(mn0, b0); mx0 = fmaxf(mx0, b0);
        s1 += b1; q1 += b1 * b1; mn1 = fminf(mn1, b1); mx1 = fmaxf(mx1, b1);
        s2 += b2; q2 += b2 * b2; mn2 = fminf(mn2, b2); mx2 = fmaxf(mx2, b2);
        if (a3) {
            float b3 = br[tid + 384];
            s3 += b3; q3 += b3 * b3; mn3 = fminf(mn3, b3); mx3 = fmaxf(mx3, b3);
        }
    }
    float degf = (float)d;
    emit_agg(n, tid,       d, degf, s0, q0, mn0, mx0, A, preb_l, agg);
    emit_agg(n, tid + 128, d, degf, s1, q1, mn1, mx1, A, preb_l, agg);
    emit_agg(n, tid + 256, d, degf, s2, q2, mn2, mx2, A, preb_l, agg);
    if (a3) emit_agg(n, tid + 384, d, degf, s3, q3, mn3, mx3, A, preb_l, agg);
}

// out[n][t*16+o2] = h.P0 + sum_j agg[j]*(P1 + c1*P2 + c2*P3)[j][o2] + postb
// stored transposed: y0T[(t*16+o2)*NN + n]
__global__ __launch_bounds__(256) void k_post(
        const float* __restrict__ hT, const float* __restrict__ agg,
        const float* __restrict__ postW_l, const float* __restrict__ postb_l,
        const int* __restrict__ offs, const float* __restrict__ ald_sum,
        float* __restrict__ y0T) {
    __shared__ float at[256][17];
    int tid = threadIdx.x;
    int n0 = blockIdx.x * 256;
    int n = n0 + tid;
    int t = blockIdx.y;
    int o0 = blockIdx.z * 8;  // o2 half
    bool alive = (n < NN);
    float c1 = 0.f, c2 = 0.f;
    if (alive) {
        float degf = (float)(offs[n + 1] - offs[n]);
        float ald = ald_sum[0] * (1.f / NN);
        float logd = logf(fmaxf(degf, 1.f) + 1.f);
        c1 = logd / ald;
        c2 = ald / logd;
    }
    float acc1[8], acc2[8], acc3[8];
#pragma unroll
    for (int i = 0; i < 8; i++) { acc1[i] = 0.f; acc2[i] = 0.f; acc3[i] = 0.f; }
    const float* W0 = postW_l + (size_t)t * 1040 * 16;
    const float* W1 = W0 + 80 * 16;
    const float* W2 = W0 + 400 * 16;
    const float* W3 = W0 + 720 * 16;
    // h part (rows 0..79) -> acc1 (coefficient 1)
    for (int f = 0; f < 80; ++f) {
        float hv = alive ? hT[(size_t)f * NN + n] : 0.f;
        const float* w = W0 + f * 16 + o0;  // wave-uniform -> s_load
#pragma unroll
        for (int i = 0; i < 8; i++) acc1[i] += hv * w[i];
    }
    // agg part: j-chunks of 16 staged in LDS
    for (int jc = 0; jc < 320; jc += 16) {
        __syncthreads();
        for (int i = tid; i < 256 * 16; i += 256) {
            int nl = i >> 4, jl = i & 15;
            int nn = n0 + nl;
            at[nl][jl] = (nn < NN) ? agg[((size_t)nn * 5 + t) * 320 + jc + jl] : 0.f;
        }
        __syncthreads();
#pragma unroll
        for (int jl = 0; jl < 16; ++jl) {
            int j = jc + jl;
            float a = at[tid][jl];
            const float* w1 = W1 + j * 16 + o0;
            const float* w2 = W2 + j * 16 + o0;
            const float* w3 = W3 + j * 16 + o0;
#pragma unroll
            for (int i = 0; i < 8; i++) {
                acc1[i] += a * w1[i];
                acc2[i] += a * w2[i];
                acc3[i] += a * w3[i];
            }
        }
    }
    if (alive) {
#pragma unroll
        for (int i = 0; i < 8; i++) {
            float v = acc1[i] + c1 * acc2[i] + c2 * acc3[i] + postb_l[t * 16 + o0 + i];
            y0T[(size_t)(t * 16 + o0 + i) * NN + n] = v;
        }
    }
}

// yT[f][n] = sum_k y0T[k][n] * linW[k][f] + linb[f]
__global__ __launch_bounds__(256) void k_lin(
        const float* __restrict__ y0T, const float* __restrict__ linW_l,
        const float* __restrict__ linb_l, float* __restrict__ yT) {
    int tid = threadIdx.x;
    int n = blockIdx.x * 256 + tid;
    int f0 = blockIdx.y * 16;
    float acc[16];
#pragma unroll
    for (int i = 0; i < 16; i++) acc[i] = 0.f;
    bool alive = (n < NN);
    for (int k = 0; k < 80; ++k) {
        float v = alive ? y0T[(size_t)k * NN + n] : 0.f;
        const float* w = linW_l + k * 80 + f0;  // wave-uniform -> s_load
#pragma unroll
        for (int i = 0; i < 16; i++) acc[i] += v * w[i];
    }
    if (alive) {
#pragma unroll
        for (int i = 0; i < 16; i++) yT[(size_t)(f0 + i) * NN + n] = acc[i] + linb_l[f0 + i];
    }
}

__global__ void k_bnstats(const float* __restrict__ yT, float* __restrict__ bnst) {
    __shared__ float r1[256], r2[256];
    int f = blockIdx.x;
    int tid = threadIdx.x;
    float s = 0.f, q = 0.f;
    for (int i = tid; i < NN; i += 256) {
        float v = yT[(size_t)f * NN + i];
        s += v; q += v * v;
    }
    r1[tid] = s; r2[tid] = q;
    __syncthreads();
    for (int st = 128; st > 0; st >>= 1) {
        if (tid < st) { r1[tid] += r1[tid + st]; r2[tid] += r2[tid + st]; }
        __syncthreads();
    }
    if (tid == 0) { bnst[f] = r1[0]; bnst[80 + f] = r2[0]; }
}

__global__ void k_bn(const float* __restrict__ yT, const float* __restrict__ bnst,
                     const float* __restrict__ gamma_l, const float* __restrict__ beta_l,
                     float* __restrict__ hT) {
    int i = blockIdx.x * 256 + threadIdx.x;
    if (i >= FEAT * NN) return;
    int f = i / NN;
    float mu = bnst[f] * (1.f / NN);
    float msq = bnst[80 + f] * (1.f / NN);
    float var = fmaxf(msq - mu * mu, 0.f);
    float v = (yT[i] - mu) * (1.f / sqrtf(var + 1e-5f)) * gamma_l[f] + beta_l[f];
    hT[i] = fmaxf(v, 0.f);
}

// ---------------- tail kernels ----------------
__global__ void k_xc(const float* __restrict__ hT, const float* __restrict__ x,
                     float* __restrict__ lxc) {
    int i = blockIdx.x * 256 + threadIdx.x;  // i = j*NN + n
    if (i >= 40 * NN) return;
    int j = i / NN, n = i - j * NN;
    float v = hT[(size_t)j * NN + n] * x[2 * n + 1] + hT[(size_t)(40 + j) * NN + n];
    lxc[(size_t)n * 40 + j] = logf(v + 1e-6f);
}

__global__ void k_logagg(const float* __restrict__ lxc, const int* __restrict__ offs,
                         const int* __restrict__ csr, const int* __restrict__ batch,
                         float* __restrict__ pooled) {
    int n = blockIdx.x;
    int tid = threadIdx.x;  // 64
    if (tid >= 40) return;
    int e0 = offs[n], e1 = offs[n + 1];
    float s = 0.f;
    for (int k = e0; k < e1; ++k) s += lxc[(size_t)csr[k] * 40 + tid];
    float v = expf(s + lxc[(size_t)n * 40 + tid]);
    atomicAdd(&pooled[batch[n] * 40 + tid], v);
}

__global__ void k_final(const float* __restrict__ pooled, const int* __restrict__ gcnt,
                        const float* __restrict__ mlW, const float* __restrict__ mlb,
                        const float* __restrict__ m1W, const float* __restrict__ m1b,
                        const float* __restrict__ m2W, const float* __restrict__ m2b,
                        float* __restrict__ out) {
    int g = threadIdx.x;
    if (g >= NG) return;
    float inv = 1.f / fmaxf((float)gcnt[g], 1.f);
    float pl[40];
#pragma unroll
    for (int j = 0; j < 40; j++) pl[j] = pooled[g * 40 + j] * inv;
    float xl = mlb[0];
#pragma unroll
    for (int j = 0; j < 40; j++) xl += pl[j] * mlW[j];
    float acc = m2b[0];
    for (int k = 0; k < 20; k++) {
        float v = m1b[k];
#pragma unroll
        for (int j = 0; j < 40; j++) v += pl[j] * m1W[j * 20 + k];
        v = 20.f - fmaxf(v, 0.f);
        acc += v * m2W[k];
    }
    out[g] = acc + xl;
}

// ---------------- launcher ----------------
extern "C" void kernel_launch(void* const* d_in, const int* in_sizes, int n_in,
                              void* d_out, int out_size, void* d_ws, size_t ws_size,
                              hipStream_t stream) {
    const float* x     = (const float*)d_in[0];
    const int*   ei    = (const int*)d_in[1];
    const int*   batch = (const int*)d_in[2];
    const float* plW   = (const float*)d_in[3];
    const float* plb   = (const float*)d_in[4];
    const float* preW  = (const float*)d_in[5];
    const float* preb  = (const float*)d_in[6];
    const float* postW = (const float*)d_in[7];
    const float* postb = (const float*)d_in[8];
    const float* linW  = (const float*)d_in[9];
    const float* linb  = (const float*)d_in[10];
    const float* bnG   = (const float*)d_in[11];
    const float* bnB   = (const float*)d_in[12];
    const float* mlW   = (const float*)d_in[13];
    const float* mlb   = (const float*)d_in[14];
    const float* m1W   = (const float*)d_in[15];
    const float* m1b   = (const float*)d_in[16];
    const float* m2W   = (const float*)d_in[17];
    const float* m2b   = (const float*)d_in[18];
    float* out = (float*)d_out;
    const int* srcp = ei;
    const int* dstp = ei + NE;

    char* p = (char*)d_ws;
    int*   deg    = (int*)(p + 0);         // 40000 B  (zeroed)
    int*   cursor = (int*)(p + 40000);     // 40000 B  (zeroed)
    int*   gcnt   = (int*)(p + 80000);     // 256 B    (zeroed)
    float* ald    = (float*)(p + 80256);   // 16 B     (zeroed)
    float* pooled = (float*)(p + 80272);   // 10240 B  (zeroed)
    float* bnst   = (float*)(p + 90512);   // 2560 B   (written each layer)
    int*   offs   = (int*)(p + 93072);     // 40016 B
    int*   csr    = (int*)(p + 133088);    // 640000 B
    float* hT     = (float*)(p + 773088);  // 3.2 MB   [80][10000]
    float* A      = (float*)(p + 3973088); // 16 MB    [10000][400]   (reused as y0T)
    float* B      = (float*)(p + 19973088);// 16 MB    [10000][400]   (reused as yT)
    float* agg    = (float*)(p + 35973088);// 64 MB    [10000][5][320] (reused as lxc)
    float* y0T = A;   // [80][10000]
    float* yT  = B;   // [80][10000]
    float* lxc = agg; // [10000][40]

    hipMemsetAsync(d_ws, 0, 90512, stream);
    k_count<<<dim3((NE + 255) / 256), 256, 0, stream>>>(dstp, deg);
    k_gcnt<<<dim3((NN + 255) / 256), 256, 0, stream>>>(batch, gcnt);
    k_scan<<<1, 256, 0, stream>>>(deg, offs);
    k_ald<<<dim3((NN + 255) / 256), 256, 0, stream>>>(deg, ald);
    k_fill<<<dim3((NE + 255) / 256), 256, 0, stream>>>(srcp, dstp, offs, cursor, csr);
    k_op0<<<dim3((FEAT * NN + 255) / 256), 256, 0, stream>>>(x, plW, plb, hT);

    for (int l = 0; l < NL; ++l) {
        const float* preW_l  = preW  + (size_t)l * NT * 160 * 80;
        const float* preb_l  = preb  + l * NT * 80;
        const float* postW_l = postW + (size_t)l * NT * 1040 * 16;
        const float* postb_l = postb + l * NT * 16;
        const float* linW_l  = linW  + l * 80 * 80;
        const float* linb_l  = linb  + l * 80;
        float* bnst_l = bnst + l * 160;
        k_mm_ab<<<dim3(625, 2), 256, 0, stream>>>(hT, preW_l, A, B);
        k_agg<<<dim3(NN), 128, 0, stream>>>(A, B, offs, csr, preb_l, ald, agg);
        k_post<<<dim3(40, 5, 2), 256, 0, stream>>>(hT, agg, postW_l, postb_l, offs, ald, y0T);
        k_lin<<<dim3(40, 5), 256, 0, stream>>>(y0T, linW_l, linb_l, yT);
        k_bnstats<<<dim3(80), 256, 0, stream>>>(yT, bnst_l);
        k_bn<<<dim3((FEAT * NN + 255) / 256), 256, 0, stream>>>(yT, bnst_l, bnG + l * 80, bnB + l * 80, hT);
    }

    k_xc<<<dim3((40 * NN + 255) / 256), 256, 0, stream>>>(hT, x, lxc);
    k_logagg<<<dim3(NN), 64, 0, stream>>>(lxc, offs, csr, batch, pooled);
    k_final<<<1, 64, 0, stream>>>(pooled, gcnt, mlW, mlb, m1W, m1b, m2W, m2b, out);
}